// Round 1
// baseline (10114.870 us; speedup 1.0000x reference)
//
#include <hip/hip_runtime.h>

// Non-local block: B=16, C=2048, IC=HW=1024.
// Pipeline: 3x conv1x1 GEMM -> f=phiT@theta -> softmax -> y=P@g -> wz GEMM -> BN -> +x
// Round 0: correctness-first. Generic fp32-accumulate tiled GEMM (vector ALU),
// bf16-staged intermediates (validates precision pipeline for later MFMA swap).
//
// Workspace layout (bytes, total ~304.02 MiB):
//   0   MiB: w_g   bf16 (4 MiB)
//   4   MiB: w_th  bf16 (4 MiB)
//   8   MiB: w_ph  bf16 (4 MiB)
//   12  MiB: w_wz  bf16 (4 MiB)
//   16  MiB: g_x   bf16 (32 MiB)  (B,IC,HW)
//   48  MiB: theta bf16 (32 MiB)  (B,IC,HW)
//   80  MiB: phiT  bf16 (32 MiB)  (B,HW,IC)
//   112 MiB: f     f32  (64 MiB)  (B,HW,HW)
//   176 MiB: P     bf16 (32 MiB)
//   208 MiB: y     bf16 (32 MiB)
//   240 MiB: wy    bf16 (64 MiB)  (B,C,HW)
//   304 MiB: stats f32  (2048*2)

__device__ __forceinline__ float bf2f(unsigned s16) {
  union { unsigned u; float f; } v; v.u = s16 << 16; return v.f;
}
__device__ __forceinline__ unsigned short f2bf(float f) {
  union { float f; unsigned u; } v; v.f = f;
  unsigned r = v.u + 0x7FFFu + ((v.u >> 16) & 1u);
  return (unsigned short)(r >> 16);
}
__device__ __forceinline__ void unpack8(uint4 u, float4& lo, float4& hi) {
  lo.x = bf2f(u.x & 0xFFFFu); lo.y = bf2f(u.x >> 16);
  lo.z = bf2f(u.y & 0xFFFFu); lo.w = bf2f(u.y >> 16);
  hi.x = bf2f(u.z & 0xFFFFu); hi.y = bf2f(u.z >> 16);
  hi.z = bf2f(u.w & 0xFFFFu); hi.w = bf2f(u.w >> 16);
}

// C = A(MxK,bf16,row) @ B(KxN,row) ; 64x64 tile, block(16,16), 4x4 per thread.
template<int B_F32, int OUT_F32, int TRANSC, int BIAS>
__global__ __launch_bounds__(256)
void gemm_k(const unsigned short* __restrict__ A, const void* __restrict__ Bv,
            void* __restrict__ Cv, const float* __restrict__ bias,
            int M, int N, int K, long sA, long sB, long sC)
{
  __shared__ float As[64][36];  // [m][k], pad to kill broadcast-bank aliasing
  __shared__ float Bs[32][64];  // [k][n]
  const int tx = threadIdx.x, ty = threadIdx.y;
  const int tid = ty * 16 + tx;
  const int bm = blockIdx.y * 64, bn = blockIdx.x * 64;
  const long zb = blockIdx.z;
  const unsigned short* Ab = A + zb * sA;
  float acc[4][4] = {};
  const int ra = tid >> 2, ca = (tid & 3) * 8;   // A tile: 64 rows x 32 k, 8 bf16/thread
  const int rb = tid >> 3, cb = (tid & 7) * 8;   // B tile: 32 k x 64 cols, 8 el/thread

  for (int k0 = 0; k0 < K; k0 += 32) {
    uint4 ua = *(const uint4*)(Ab + (long)(bm + ra) * K + (k0 + ca));
    float4 alo, ahi; unpack8(ua, alo, ahi);
    *(float4*)&As[ra][ca]     = alo;
    *(float4*)&As[ra][ca + 4] = ahi;
    if (B_F32) {
      const float* Bp = (const float*)Bv + zb * sB + (long)(k0 + rb) * N + (bn + cb);
      *(float4*)&Bs[rb][cb]     = *(const float4*)Bp;
      *(float4*)&Bs[rb][cb + 4] = *(const float4*)(Bp + 4);
    } else {
      const unsigned short* Bp = (const unsigned short*)Bv + zb * sB + (long)(k0 + rb) * N + (bn + cb);
      uint4 ub = *(const uint4*)Bp;
      float4 blo, bhi; unpack8(ub, blo, bhi);
      *(float4*)&Bs[rb][cb]     = blo;
      *(float4*)&Bs[rb][cb + 4] = bhi;
    }
    __syncthreads();
#pragma unroll
    for (int k = 0; k < 32; k += 4) {
      float4 b0 = *(const float4*)&Bs[k + 0][tx * 4];
      float4 b1 = *(const float4*)&Bs[k + 1][tx * 4];
      float4 b2 = *(const float4*)&Bs[k + 2][tx * 4];
      float4 b3 = *(const float4*)&Bs[k + 3][tx * 4];
#pragma unroll
      for (int i = 0; i < 4; ++i) {
        float4 a = *(const float4*)&As[ty * 4 + i][k];
        acc[i][0] += a.x * b0.x + a.y * b1.x + a.z * b2.x + a.w * b3.x;
        acc[i][1] += a.x * b0.y + a.y * b1.y + a.z * b2.y + a.w * b3.y;
        acc[i][2] += a.x * b0.z + a.y * b1.z + a.z * b2.z + a.w * b3.z;
        acc[i][3] += a.x * b0.w + a.y * b1.w + a.z * b2.w + a.w * b3.w;
      }
    }
    __syncthreads();
  }

#pragma unroll
  for (int i = 0; i < 4; ++i) {
    const int row = bm + ty * 4 + i;
    const float bv = BIAS ? bias[row] : 0.0f;
    float4 r;
    r.x = acc[i][0] + bv; r.y = acc[i][1] + bv;
    r.z = acc[i][2] + bv; r.w = acc[i][3] + bv;
    if (OUT_F32) {
      float* C = (float*)Cv + zb * sC;
      *(float4*)&C[(long)row * N + bn + tx * 4] = r;
    } else if (!TRANSC) {
      unsigned short* C = (unsigned short*)Cv + zb * sC;
      ushort4 o; o.x = f2bf(r.x); o.y = f2bf(r.y); o.z = f2bf(r.z); o.w = f2bf(r.w);
      *(ushort4*)&C[(long)row * N + bn + tx * 4] = o;
    } else {  // C^T store (used for phiT)
      unsigned short* C = (unsigned short*)Cv + zb * sC;
      C[(long)(bn + tx * 4 + 0) * M + row] = f2bf(r.x);
      C[(long)(bn + tx * 4 + 1) * M + row] = f2bf(r.y);
      C[(long)(bn + tx * 4 + 2) * M + row] = f2bf(r.z);
      C[(long)(bn + tx * 4 + 3) * M + row] = f2bf(r.w);
    }
  }
}

__global__ void f2bf_k(const float* __restrict__ in, unsigned short* __restrict__ out, long n4)
{
  long i = blockIdx.x * (long)blockDim.x + threadIdx.x;
  const long st = (long)gridDim.x * blockDim.x;
  for (; i < n4; i += st) {
    float4 v = *(const float4*)(in + i * 4);
    ushort4 o; o.x = f2bf(v.x); o.y = f2bf(v.y); o.z = f2bf(v.z); o.w = f2bf(v.w);
    *(ushort4*)(out + i * 4) = o;
  }
}

// one block per row of f (16384 rows x 1024)
__global__ __launch_bounds__(256)
void softmax_k(const float* __restrict__ f, unsigned short* __restrict__ P)
{
  const long row = blockIdx.x;
  const float* fr = f + row * 1024;
  unsigned short* pr = P + row * 1024;
  const int tid = threadIdx.x;
  const int lane = tid & 63, wid = tid >> 6;
  float v[4];
  float mx = -1e30f;
#pragma unroll
  for (int i = 0; i < 4; ++i) { v[i] = fr[tid + i * 256]; mx = fmaxf(mx, v[i]); }
  for (int o = 32; o; o >>= 1) mx = fmaxf(mx, __shfl_xor(mx, o));
  __shared__ float redm[4];
  if (!lane) redm[wid] = mx;
  __syncthreads();
  mx = fmaxf(fmaxf(redm[0], redm[1]), fmaxf(redm[2], redm[3]));
  float s = 0.f;
#pragma unroll
  for (int i = 0; i < 4; ++i) { v[i] = __expf(v[i] - mx); s += v[i]; }
  for (int o = 32; o; o >>= 1) s += __shfl_xor(s, o);
  __shared__ float reds[4];
  if (!lane) reds[wid] = s;
  __syncthreads();
  s = reds[0] + reds[1] + reds[2] + reds[3];
  const float inv = 1.0f / s;
#pragma unroll
  for (int i = 0; i < 4; ++i) pr[tid + i * 256] = f2bf(v[i] * inv);
}

// one block per channel c: mean/var over (B=16, HW=1024) of wy
__global__ __launch_bounds__(256)
void bn_stats_k(const unsigned short* __restrict__ wy, float* __restrict__ stats)
{
  const int c = blockIdx.x;
  const int tid = threadIdx.x;
  const int lane = tid & 63, wid = tid >> 6;
  float s = 0.f, ss = 0.f;
  for (int b = 0; b < 16; ++b) {
    const unsigned short* p = wy + ((long)b * 2048 + c) * 1024 + tid * 4;
    uint2 u = *(const uint2*)p;
    float v0 = bf2f(u.x & 0xFFFFu), v1 = bf2f(u.x >> 16);
    float v2 = bf2f(u.y & 0xFFFFu), v3 = bf2f(u.y >> 16);
    s += v0 + v1 + v2 + v3;
    ss += v0 * v0 + v1 * v1 + v2 * v2 + v3 * v3;
  }
  for (int o = 32; o; o >>= 1) { s += __shfl_xor(s, o); ss += __shfl_xor(ss, o); }
  __shared__ float rs[4], rss[4];
  if (!lane) { rs[wid] = s; rss[wid] = ss; }
  __syncthreads();
  if (tid == 0) {
    s = rs[0] + rs[1] + rs[2] + rs[3];
    ss = rss[0] + rss[1] + rss[2] + rss[3];
    const float mean = s * (1.0f / 16384.0f);
    const float var = ss * (1.0f / 16384.0f) - mean * mean;
    stats[2 * c] = mean;
    stats[2 * c + 1] = rsqrtf(var + 1e-5f);
  }
}

// out = (wy - mean)*rstd*gamma + beta + x_this
__global__ void bn_final_k(const unsigned short* __restrict__ wy,
                           const float* __restrict__ x_this,
                           const float* __restrict__ stats,
                           const float* __restrict__ gamma,
                           const float* __restrict__ beta,
                           float* __restrict__ out, long n4)
{
  long i = blockIdx.x * (long)blockDim.x + threadIdx.x;
  const long st = (long)gridDim.x * blockDim.x;
  for (; i < n4; i += st) {
    const long e = i * 4;
    const int c = (int)((e >> 10) & 2047);
    const float mean = stats[2 * c], rstd = stats[2 * c + 1];
    const float ga = gamma[c] * rstd;
    const float be = beta[c] - mean * ga;
    uint2 u = *(const uint2*)(wy + e);
    float4 x = *(const float4*)(x_this + e);
    float4 o;
    o.x = bf2f(u.x & 0xFFFFu) * ga + be + x.x;
    o.y = bf2f(u.x >> 16)     * ga + be + x.y;
    o.z = bf2f(u.y & 0xFFFFu) * ga + be + x.z;
    o.w = bf2f(u.y >> 16)     * ga + be + x.w;
    *(float4*)(out + e) = o;
  }
}

extern "C" void kernel_launch(void* const* d_in, const int* in_sizes, int n_in,
                              void* d_out, int out_size, void* d_ws, size_t ws_size,
                              hipStream_t stream) {
  const float* x_this  = (const float*)d_in[0];
  const float* x_other = (const float*)d_in[1];
  const float* g_w     = (const float*)d_in[2];
  const float* g_b     = (const float*)d_in[3];
  const float* theta_w = (const float*)d_in[4];
  const float* theta_b = (const float*)d_in[5];
  const float* phi_w   = (const float*)d_in[6];
  const float* phi_b   = (const float*)d_in[7];
  const float* wz_w    = (const float*)d_in[8];
  const float* wz_b    = (const float*)d_in[9];
  const float* bn_gamma= (const float*)d_in[10];
  const float* bn_beta = (const float*)d_in[11];
  float* out = (float*)d_out;
  char* ws = (char*)d_ws;
  const size_t MB = 1ull << 20;

  unsigned short* wg  = (unsigned short*)(ws + 0 * MB);
  unsigned short* wth = (unsigned short*)(ws + 4 * MB);
  unsigned short* wph = (unsigned short*)(ws + 8 * MB);
  unsigned short* wwz = (unsigned short*)(ws + 12 * MB);
  unsigned short* gx  = (unsigned short*)(ws + 16 * MB);
  unsigned short* th  = (unsigned short*)(ws + 48 * MB);
  unsigned short* phT = (unsigned short*)(ws + 80 * MB);
  float*          fb  = (float*)         (ws + 112 * MB);
  unsigned short* P   = (unsigned short*)(ws + 176 * MB);
  unsigned short* y   = (unsigned short*)(ws + 208 * MB);
  unsigned short* wy  = (unsigned short*)(ws + 240 * MB);
  float*          st  = (float*)         (ws + 304 * MB);

  const long S1M = 1l << 20;           // 1024*1024
  const long S2M = 2l << 20;           // 2048*1024
  dim3 blk(16, 16);

  // stage weights to bf16
  f2bf_k<<<dim3(512), dim3(256), 0, stream>>>(g_w,     wg,  2097152 / 4);
  f2bf_k<<<dim3(512), dim3(256), 0, stream>>>(theta_w, wth, 2097152 / 4);
  f2bf_k<<<dim3(512), dim3(256), 0, stream>>>(phi_w,   wph, 2097152 / 4);
  f2bf_k<<<dim3(512), dim3(256), 0, stream>>>(wz_w,    wwz, 2097152 / 4);

  // g_x = g_w @ x_this ; theta = theta_w @ x_this ; phiT = (phi_w @ x_other)^T
  gemm_k<1, 0, 0, 1><<<dim3(16, 16, 16), blk, 0, stream>>>(wg,  x_this,  gx,  g_b,     1024, 1024, 2048, 0, S2M, S1M);
  gemm_k<1, 0, 0, 1><<<dim3(16, 16, 16), blk, 0, stream>>>(wth, x_this,  th,  theta_b, 1024, 1024, 2048, 0, S2M, S1M);
  gemm_k<1, 0, 1, 1><<<dim3(16, 16, 16), blk, 0, stream>>>(wph, x_other, phT, phi_b,   1024, 1024, 2048, 0, S2M, S1M);
  // f = phiT @ theta  (f32 out)
  gemm_k<0, 1, 0, 0><<<dim3(16, 16, 16), blk, 0, stream>>>(phT, th, fb, nullptr, 1024, 1024, 1024, S1M, S1M, S1M);
  // P = softmax(f) (bf16)
  softmax_k<<<dim3(16384), dim3(256), 0, stream>>>(fb, P);
  // y = P @ g_x
  gemm_k<0, 0, 0, 0><<<dim3(16, 16, 16), blk, 0, stream>>>(P, gx, y, nullptr, 1024, 1024, 1024, S1M, S1M, S1M);
  // wy = wz_w @ y + wz_b
  gemm_k<0, 0, 0, 1><<<dim3(16, 32, 16), blk, 0, stream>>>(wwz, y, wy, wz_b, 2048, 1024, 1024, 0, S1M, S2M);
  // BN stats + final
  bn_stats_k<<<dim3(2048), dim3(256), 0, stream>>>(wy, st);
  bn_final_k<<<dim3(4096), dim3(256), 0, stream>>>(wy, x_this, st, bn_gamma, bn_beta, out, 33554432 / 4);
  (void)ws_size; (void)n_in; (void)in_sizes; (void)out_size;
}

// Round 5
// 1028.366 us; speedup vs baseline: 9.8359x; 9.8359x over previous
//
#include <hip/hip_runtime.h>

// Non-local block: B=16, C=2048, IC=HW=1024.
// R1: MFMA bf16 GEMM (m97 structure: 128x128 tile, BK=32, global_load_lds x16,
// swizzled LDS, mfma_f32_16x16x32_bf16). All GEMMs use A(MxK) @ Bt(NxK) form:
//   xtT/xoT = transpose(x) bf16 (HW x C)
//   gT/thT/phT = xT @ w^T + b      (HW x IC, transposed conv out)
//   f   = phT @ thT^T (f32)        -> softmax -> P (bf16)
//   yT  = gT @ P^T                 (HW_j x HW_i)
//   wy  = wz @ yT^T + b            (C x HW)
//   out = BN(wy) + x_this
//
// Workspace (<= 240 MiB + stats; buffers reused after liveness ends):
//   0:wg 4:wth 8:wph 12:wwz (bf16 weights)
//   16-80:  xtT (64 MiB)  -> reused for fb (f32, 64 MiB) after convs
//   80-144: xoT (64 MiB)  -> reused for P (32 MiB @80) + yT (32 MiB @112)
//   144-176: gT   176-208: thT   208-240: phT
//   176-240: wy (64 MiB, overwrites thT/phT after they die)
//   240: stats

typedef __attribute__((ext_vector_type(4))) float f32x4;
typedef __attribute__((ext_vector_type(8))) short bf16x8;

__device__ __forceinline__ float bf2f(unsigned s16) {
  union { unsigned u; float f; } v; v.u = s16 << 16; return v.f;
}
__device__ __forceinline__ unsigned short f2bf(float f) {
  union { float f; unsigned u; } v; v.f = f;
  unsigned r = v.u + 0x7FFFu + ((v.u >> 16) & 1u);
  return (unsigned short)(r >> 16);
}

__device__ __forceinline__ void gload_lds16(const unsigned short* g, unsigned short* l) {
  __builtin_amdgcn_global_load_lds((const __attribute__((address_space(1))) void*)g,
                                   (__attribute__((address_space(3))) void*)l, 16, 0, 0);
}

// C(MxN) = A(MxK) @ Bt(NxK)^T, bf16 in, fp32 accum.
// 128x128 tile, 4 waves (each one 64x64 quadrant of 4x4 16x16 fragments), BK=32.
// LDS slot-swizzle: 16B slot s at row r holds global slot s ^ ((r>>1)&3).
template<int OUT_F32, int BIAS_MODE>   // BIAS_MODE: 0 none, 1 bias[row], 2 bias[col]
__global__ __launch_bounds__(256)
void mm_bt(const unsigned short* __restrict__ A, const unsigned short* __restrict__ Bt,
           void* __restrict__ Cv, const float* __restrict__ bias,
           int M, int N, int K, long sA, long sB, long sC)
{
  __shared__ __align__(16) unsigned short lds[8192];  // A: [0,4096) els, B: [4096,8192)
  const int tid = threadIdx.x;
  const int wave = tid >> 6, lane = tid & 63;
  const int bm = blockIdx.y * 128, bn = blockIdx.x * 128;
  const long z = blockIdx.z;
  const unsigned short* Ab = A + z * sA;
  const unsigned short* Bb = Bt + z * sB;

  // --- staging: each wave stages 2 chunks of A and 2 of B (chunk = 16 rows x 32k = 1 KiB)
  const int c0 = wave * 2, c1 = wave * 2 + 1;
  const int sr0 = c0 * 16 + (lane >> 2), sr1 = c1 * 16 + (lane >> 2);
  const int ss0 = (lane & 3) ^ ((sr0 >> 1) & 3);
  const int ss1 = (lane & 3) ^ ((sr1 >> 1) & 3);
  const unsigned short* gA0 = Ab + (long)(bm + sr0) * K + ss0 * 8;
  const unsigned short* gA1 = Ab + (long)(bm + sr1) * K + ss1 * 8;
  const unsigned short* gB0 = Bb + (long)(bn + sr0) * K + ss0 * 8;
  const unsigned short* gB1 = Bb + (long)(bn + sr1) * K + ss1 * 8;
  unsigned short* lA0 = &lds[c0 * 512];
  unsigned short* lA1 = &lds[c1 * 512];
  unsigned short* lB0 = &lds[4096 + c0 * 512];
  unsigned short* lB1 = &lds[4096 + c1 * 512];

  // --- fragment read offsets (element units); swizzle key depends only on lane
  const int wr = wave >> 1, wc = wave & 1;
  const int rA = lane & 15, kg = lane >> 4;
  const int slot = kg ^ ((rA >> 1) & 3);
  const int aoff = (wr * 64 + rA) * 32 + slot * 8;          // + m*512
  const int boff = 4096 + (wc * 64 + rA) * 32 + slot * 8;   // + n*512

  f32x4 acc[4][4];
#pragma unroll
  for (int i = 0; i < 4; ++i)
#pragma unroll
    for (int j = 0; j < 4; ++j) acc[i][j] = (f32x4)0.f;

  for (int k0 = 0; k0 < K; k0 += 32) {
    gload_lds16(gA0 + k0, lA0);
    gload_lds16(gA1 + k0, lA1);
    gload_lds16(gB0 + k0, lB0);
    gload_lds16(gB1 + k0, lB1);
    __syncthreads();   // compiler drains vmcnt before s_barrier
    bf16x8 af[4], bfr[4];
#pragma unroll
    for (int m = 0; m < 4; ++m) af[m] = *(const bf16x8*)&lds[aoff + m * 512];
#pragma unroll
    for (int n = 0; n < 4; ++n) bfr[n] = *(const bf16x8*)&lds[boff + n * 512];
#pragma unroll
    for (int m = 0; m < 4; ++m)
#pragma unroll
      for (int n = 0; n < 4; ++n)
        acc[m][n] = __builtin_amdgcn_mfma_f32_16x16x32_bf16(af[m], bfr[n], acc[m][n], 0, 0, 0);
    __syncthreads();
  }

  // --- epilogue: C/D layout col = lane&15, row = (lane>>4)*4 + reg
  const int col0 = bn + wc * 64 + (lane & 15);
  const int row0 = bm + wr * 64 + (lane >> 4) * 4;
#pragma unroll
  for (int m = 0; m < 4; ++m) {
#pragma unroll
    for (int n = 0; n < 4; ++n) {
      const int cc = col0 + n * 16;
      float bcol = (BIAS_MODE == 2) ? bias[cc] : 0.0f;
#pragma unroll
      for (int r = 0; r < 4; ++r) {
        const int rr = row0 + m * 16 + r;
        float v = acc[m][n][r] + ((BIAS_MODE == 1) ? bias[rr] : bcol);
        if (OUT_F32) ((float*)Cv)[z * sC + (long)rr * N + cc] = v;
        else ((unsigned short*)Cv)[z * sC + (long)rr * N + cc] = f2bf(v);
      }
    }
  }
}

// transpose + f32->bf16: in (z, R, CC) f32 -> out (z, CC, R) bf16. 32x32 tiles.
__global__ __launch_bounds__(256)
void tr_bf_k(const float* __restrict__ in, unsigned short* __restrict__ out, int R, int CC)
{
  __shared__ float t[32][33];
  const long z = blockIdx.z;
  const int r0 = blockIdx.y * 32, c0 = blockIdx.x * 32;
  const float* ip = in + z * (long)R * CC;
  unsigned short* op = out + z * (long)R * CC;
  const int tx = threadIdx.x & 31, ty = threadIdx.x >> 5;
#pragma unroll
  for (int i = 0; i < 32; i += 8)
    t[ty + i][tx] = ip[(long)(r0 + ty + i) * CC + c0 + tx];
  __syncthreads();
  const int oc = threadIdx.x >> 3;        // col within tile (CC dim)
  const int orr = (threadIdx.x & 7) * 4;  // row within tile (R dim), x4
  ushort4 o;
  o.x = f2bf(t[orr + 0][oc]); o.y = f2bf(t[orr + 1][oc]);
  o.z = f2bf(t[orr + 2][oc]); o.w = f2bf(t[orr + 3][oc]);
  *(ushort4*)&op[(long)(c0 + oc) * R + r0 + orr] = o;
}

__global__ void f2bf_k(const float* __restrict__ in, unsigned short* __restrict__ out, long n4)
{
  long i = blockIdx.x * (long)blockDim.x + threadIdx.x;
  const long st = (long)gridDim.x * blockDim.x;
  for (; i < n4; i += st) {
    float4 v = *(const float4*)(in + i * 4);
    ushort4 o; o.x = f2bf(v.x); o.y = f2bf(v.y); o.z = f2bf(v.z); o.w = f2bf(v.w);
    *(ushort4*)(out + i * 4) = o;
  }
}

// one block per row of f (16384 rows x 1024)
__global__ __launch_bounds__(256)
void softmax_k(const float* __restrict__ f, unsigned short* __restrict__ P)
{
  const long row = blockIdx.x;
  const float* fr = f + row * 1024;
  unsigned short* pr = P + row * 1024;
  const int tid = threadIdx.x;
  const int lane = tid & 63, wid = tid >> 6;
  float v[4];
  float mx = -1e30f;
#pragma unroll
  for (int i = 0; i < 4; ++i) { v[i] = fr[tid + i * 256]; mx = fmaxf(mx, v[i]); }
  for (int o = 32; o; o >>= 1) mx = fmaxf(mx, __shfl_xor(mx, o));
  __shared__ float redm[4];
  if (!lane) redm[wid] = mx;
  __syncthreads();
  mx = fmaxf(fmaxf(redm[0], redm[1]), fmaxf(redm[2], redm[3]));
  float s = 0.f;
#pragma unroll
  for (int i = 0; i < 4; ++i) { v[i] = __expf(v[i] - mx); s += v[i]; }
  for (int o = 32; o; o >>= 1) s += __shfl_xor(s, o);
  __shared__ float reds[4];
  if (!lane) reds[wid] = s;
  __syncthreads();
  s = reds[0] + reds[1] + reds[2] + reds[3];
  const float inv = 1.0f / s;
#pragma unroll
  for (int i = 0; i < 4; ++i) pr[tid + i * 256] = f2bf(v[i] * inv);
}

// one block per channel c: mean/var over (B=16, HW=1024) of wy (bf16, (b,C,HW))
__global__ __launch_bounds__(256)
void bn_stats_k(const unsigned short* __restrict__ wy, float* __restrict__ stats)
{
  const int c = blockIdx.x;
  const int tid = threadIdx.x;
  const int lane = tid & 63, wid = tid >> 6;
  float s = 0.f, ss = 0.f;
  for (int b = 0; b < 16; ++b) {
    const unsigned short* p = wy + ((long)b * 2048 + c) * 1024 + tid * 4;
    uint2 u = *(const uint2*)p;
    float v0 = bf2f(u.x & 0xFFFFu), v1 = bf2f(u.x >> 16);
    float v2 = bf2f(u.y & 0xFFFFu), v3 = bf2f(u.y >> 16);
    s += v0 + v1 + v2 + v3;
    ss += v0 * v0 + v1 * v1 + v2 * v2 + v3 * v3;
  }
  for (int o = 32; o; o >>= 1) { s += __shfl_xor(s, o); ss += __shfl_xor(ss, o); }
  __shared__ float rs[4], rss[4];
  if (!lane) { rs[wid] = s; rss[wid] = ss; }
  __syncthreads();
  if (tid == 0) {
    s = rs[0] + rs[1] + rs[2] + rs[3];
    ss = rss[0] + rss[1] + rss[2] + rss[3];
    const float mean = s * (1.0f / 16384.0f);
    const float var = ss * (1.0f / 16384.0f) - mean * mean;
    stats[2 * c] = mean;
    stats[2 * c + 1] = rsqrtf(var + 1e-5f);
  }
}

__global__ void bn_final_k(const unsigned short* __restrict__ wy,
                           const float* __restrict__ x_this,
                           const float* __restrict__ stats,
                           const float* __restrict__ gamma,
                           const float* __restrict__ beta,
                           float* __restrict__ out, long n4)
{
  long i = blockIdx.x * (long)blockDim.x + threadIdx.x;
  const long st = (long)gridDim.x * blockDim.x;
  for (; i < n4; i += st) {
    const long e = i * 4;
    const int c = (int)((e >> 10) & 2047);
    const float mean = stats[2 * c], rstd = stats[2 * c + 1];
    const float ga = gamma[c] * rstd;
    const float be = beta[c] - mean * ga;
    uint2 u = *(const uint2*)(wy + e);
    float4 x = *(const float4*)(x_this + e);
    float4 o;
    o.x = bf2f(u.x & 0xFFFFu) * ga + be + x.x;
    o.y = bf2f(u.x >> 16)     * ga + be + x.y;
    o.z = bf2f(u.y & 0xFFFFu) * ga + be + x.z;
    o.w = bf2f(u.y >> 16)     * ga + be + x.w;
    *(float4*)(out + e) = o;
  }
}

extern "C" void kernel_launch(void* const* d_in, const int* in_sizes, int n_in,
                              void* d_out, int out_size, void* d_ws, size_t ws_size,
                              hipStream_t stream) {
  const float* x_this  = (const float*)d_in[0];
  const float* x_other = (const float*)d_in[1];
  const float* g_w     = (const float*)d_in[2];
  const float* g_b     = (const float*)d_in[3];
  const float* theta_w = (const float*)d_in[4];
  const float* theta_b = (const float*)d_in[5];
  const float* phi_w   = (const float*)d_in[6];
  const float* phi_b   = (const float*)d_in[7];
  const float* wz_w    = (const float*)d_in[8];
  const float* wz_b    = (const float*)d_in[9];
  const float* bn_gamma= (const float*)d_in[10];
  const float* bn_beta = (const float*)d_in[11];
  float* out = (float*)d_out;
  char* ws = (char*)d_ws;
  const size_t MB = 1ull << 20;

  unsigned short* wg  = (unsigned short*)(ws + 0 * MB);
  unsigned short* wth = (unsigned short*)(ws + 4 * MB);
  unsigned short* wph = (unsigned short*)(ws + 8 * MB);
  unsigned short* wwz = (unsigned short*)(ws + 12 * MB);
  unsigned short* xtT = (unsigned short*)(ws + 16 * MB);   // (16,1024,2048) bf16
  unsigned short* xoT = (unsigned short*)(ws + 80 * MB);   // (16,1024,2048) bf16
  unsigned short* gT  = (unsigned short*)(ws + 144 * MB);  // (16,1024,1024)
  unsigned short* thT = (unsigned short*)(ws + 176 * MB);
  unsigned short* phT = (unsigned short*)(ws + 208 * MB);
  float*          fb  = (float*)         (ws + 16 * MB);   // reuse xtT (64 MiB f32)
  unsigned short* P   = (unsigned short*)(ws + 80 * MB);   // reuse xoT (32 MiB)
  unsigned short* yT  = (unsigned short*)(ws + 112 * MB);  // reuse xoT (32 MiB)
  unsigned short* wy  = (unsigned short*)(ws + 176 * MB);  // reuse thT+phT (64 MiB)
  float*          st  = (float*)         (ws + 240 * MB);

  const long S1M = 1l << 20;   // 1024*1024
  const long S2M = 2l << 20;   // 2048*1024 (= 1024*2048)

  // weights -> bf16
  f2bf_k<<<dim3(512), dim3(256), 0, stream>>>(g_w,     wg,  2097152 / 4);
  f2bf_k<<<dim3(512), dim3(256), 0, stream>>>(theta_w, wth, 2097152 / 4);
  f2bf_k<<<dim3(512), dim3(256), 0, stream>>>(phi_w,   wph, 2097152 / 4);
  f2bf_k<<<dim3(512), dim3(256), 0, stream>>>(wz_w,    wwz, 2097152 / 4);
  // x transposes -> bf16 (HW x C per batch)
  tr_bf_k<<<dim3(32, 64, 16), dim3(256), 0, stream>>>(x_this,  xtT, 2048, 1024);
  tr_bf_k<<<dim3(32, 64, 16), dim3(256), 0, stream>>>(x_other, xoT, 2048, 1024);

  // conv^T GEMMs: (HW x C) @ (IC x C)^T -> (HW x IC), col-bias
  mm_bt<0, 2><<<dim3(8, 8, 16), dim3(256), 0, stream>>>(xtT, wg,  gT,  g_b,     1024, 1024, 2048, S2M, 0, S1M);
  mm_bt<0, 2><<<dim3(8, 8, 16), dim3(256), 0, stream>>>(xtT, wth, thT, theta_b, 1024, 1024, 2048, S2M, 0, S1M);
  mm_bt<0, 2><<<dim3(8, 8, 16), dim3(256), 0, stream>>>(xoT, wph, phT, phi_b,   1024, 1024, 2048, S2M, 0, S1M);
  // f = phT @ thT^T (f32 out)   [xtT dead after this point's inputs were read]
  mm_bt<1, 0><<<dim3(8, 8, 16), dim3(256), 0, stream>>>(phT, thT, fb, nullptr, 1024, 1024, 1024, S1M, S1M, S1M);
  // P = softmax(f)
  softmax_k<<<dim3(16384), dim3(256), 0, stream>>>(fb, P);
  // yT = gT @ P^T
  mm_bt<0, 0><<<dim3(8, 8, 16), dim3(256), 0, stream>>>(gT, P, yT, nullptr, 1024, 1024, 1024, S1M, S1M, S1M);
  // wy = wz @ yT^T + wz_b (row-bias)
  mm_bt<0, 1><<<dim3(8, 16, 16), dim3(256), 0, stream>>>(wwz, yT, wy, wz_b, 2048, 1024, 1024, 0, S1M, S2M);
  // BN + residual
  bn_stats_k<<<dim3(2048), dim3(256), 0, stream>>>(wy, st);
  bn_final_k<<<dim3(4096), dim3(256), 0, stream>>>(wy, x_this, st, bn_gamma, bn_beta, out, 33554432 / 4);
  (void)ws_size; (void)n_in; (void)in_sizes; (void)out_size;
}

// Round 9
// 810.529 us; speedup vs baseline: 12.4793x; 1.2688x over previous
//
#include <hip/hip_runtime.h>

// Non-local block: B=16, C=2048, IC=HW=1024.
// R5: GEMM upgraded to counted-vmcnt double-buffered pipeline (T3/T4-lite):
//   BK=64, LDS dbuf (2x32KB), raw s_barrier + manual s_waitcnt, distance-2
//   prefetch via global_load_lds, vmcnt(8) in steady state (never 0 in loop),
//   XCD-aware block swizzle (T1). Same math pipeline as R1:
//   xtT/xoT = transpose(x) bf16 -> gT/thT/phT = xT @ w^T + b -> f = phT@thT^T
//   -> softmax -> yT = gT@P^T -> wy = wz@yT^T + b -> BN -> +x_this.

typedef __attribute__((ext_vector_type(4))) float f32x4;
typedef __attribute__((ext_vector_type(8))) short bf16x8;

__device__ __forceinline__ float bf2f(unsigned s16) {
  union { unsigned u; float f; } v; v.u = s16 << 16; return v.f;
}
__device__ __forceinline__ unsigned short f2bf(float f) {
  union { float f; unsigned u; } v; v.f = f;
  unsigned r = v.u + 0x7FFFu + ((v.u >> 16) & 1u);
  return (unsigned short)(r >> 16);
}

__device__ __forceinline__ void gload_lds16(const unsigned short* g, unsigned short* l) {
  __builtin_amdgcn_global_load_lds((const __attribute__((address_space(1))) void*)g,
                                   (__attribute__((address_space(3))) void*)l, 16, 0, 0);
}

#define SWAIT_VM8()   asm volatile("s_waitcnt vmcnt(8)" ::: "memory")
#define SWAIT_VM0()   asm volatile("s_waitcnt vmcnt(0)" ::: "memory")
#define SWAIT_LGKM0() asm volatile("s_waitcnt lgkmcnt(0)" ::: "memory")
#define SCHED_BAR()   __builtin_amdgcn_sched_barrier(0)
#define SBAR()        __builtin_amdgcn_s_barrier()

// C(MxN) = A(MxK) @ Bt(NxK)^T, bf16 in, fp32 accum. 128x128 tile, 4 waves,
// BK=64 (2 k-steps of 32), double-buffered LDS (64 KiB), counted-vmcnt pipeline.
// LDS slot-swizzle: 16B slot s of row r holds global k-slot s ^ (r&7)
// (staged via pre-swizzled GLOBAL source; LDS dest stays linear — rule #21).
// Grid: 1-D nwg = nbx*nby*16, XCD-swizzled; x fastest (A-panel L2 reuse).
template<int OUT_F32, int BIAS_MODE>   // BIAS_MODE: 0 none, 1 bias[row], 2 bias[col]
__global__ __launch_bounds__(256, 2)
void mm_bt(const unsigned short* __restrict__ A, const unsigned short* __restrict__ Bt,
           void* __restrict__ Cv, const float* __restrict__ bias,
           int N, int K, long sA, long sB, long sC, int nbx, int nby)
{
  __shared__ __align__(16) unsigned short lds[32768];  // buf(t&1): A@[b*16384), B@[b*16384+8192)
  const int tid = threadIdx.x;
  const int wave = tid >> 6, lane = tid & 63;

  // --- XCD swizzle: consecutive logical tiles land on the same XCD
  const int nwg = nbx * nby * 16;
  const int cpx = nwg >> 3;                     // nwg % 8 == 0 for all our launches
  const int swz = (blockIdx.x & 7) * cpx + (blockIdx.x >> 3);
  const int bx = swz % nbx;
  const int rem = swz / nbx;
  const int by = rem % nby;
  const long z = rem / nby;
  const int bm = by * 128, bn = bx * 128;

  const unsigned short* Ab = A + z * sA;
  const unsigned short* Bb = Bt + z * sB;

  // --- staging address precompute: 4 A-loads + 4 B-loads per thread per K-tile.
  // 16B-slot q = s*256 + tid -> row = q>>3, slot = q&7; LDS linear = q*8 els;
  // global k-slot = slot ^ (row&7).
  long gAo[4], gBo[4];
  int  lEo[4];
#pragma unroll
  for (int s = 0; s < 4; ++s) {
    const int q = s * 256 + tid;
    const int row = q >> 3, sl = q & 7;
    const int gsl = sl ^ (row & 7);
    gAo[s] = (long)(bm + row) * K + gsl * 8;
    gBo[s] = (long)(bn + row) * K + gsl * 8;
    lEo[s] = q * 8;
  }

  // --- fragment read offsets: A row r=wr*64+m*16+(lane&15), k-slot kk*4+(lane>>4)
  const int wr = wave >> 1, wc = wave & 1;
  const int l15 = lane & 15, kgl = lane >> 4;
  int aoff[2][4], boff[2][4];
#pragma unroll
  for (int kk = 0; kk < 2; ++kk)
#pragma unroll
    for (int m = 0; m < 4; ++m) {
      const int ra = wr * 64 + m * 16 + l15;
      aoff[kk][m] = ra * 64 + ((kk * 4 + kgl) ^ (ra & 7)) * 8;
      const int rb = wc * 64 + m * 16 + l15;
      boff[kk][m] = 8192 + rb * 64 + ((kk * 4 + kgl) ^ (rb & 7)) * 8;
    }

  const int NT = K >> 6;

  // prologue: stage tiles 0 and 1; wait tile0 (8 newest = tile1 may fly)
  {
    unsigned short* l0 = &lds[0];
#pragma unroll
    for (int s = 0; s < 4; ++s) gload_lds16(Ab + gAo[s], l0 + lEo[s]);
#pragma unroll
    for (int s = 0; s < 4; ++s) gload_lds16(Bb + gBo[s], l0 + 8192 + lEo[s]);
    unsigned short* l1 = &lds[16384];
#pragma unroll
    for (int s = 0; s < 4; ++s) gload_lds16(Ab + gAo[s] + 64, l1 + lEo[s]);
#pragma unroll
    for (int s = 0; s < 4; ++s) gload_lds16(Bb + gBo[s] + 64, l1 + 8192 + lEo[s]);
  }
  SWAIT_VM8(); SCHED_BAR();
  SBAR();

  f32x4 acc[4][4];
#pragma unroll
  for (int i = 0; i < 4; ++i)
#pragma unroll
    for (int j = 0; j < 4; ++j) acc[i][j] = (f32x4)0.f;

  for (int t = 0; t < NT; ++t) {
    const int bufo = (t & 1) * 16384;
    bf16x8 af[2][4], bg[2][4];
#pragma unroll
    for (int kk = 0; kk < 2; ++kk)
#pragma unroll
      for (int m = 0; m < 4; ++m) {
        af[kk][m] = *(const bf16x8*)&lds[bufo + aoff[kk][m]];
        bg[kk][m] = *(const bf16x8*)&lds[bufo + boff[kk][m]];
      }
    SWAIT_LGKM0(); SCHED_BAR();
    SBAR();                       // A: all waves retired reads of buf(t&1)
    SCHED_BAR();
    if (t + 2 < NT) {             // stage tile t+2 into the now-dead buffer
      const long kb = (long)(t + 2) * 64;
      unsigned short* lb = &lds[bufo];
#pragma unroll
      for (int s = 0; s < 4; ++s) gload_lds16(Ab + gAo[s] + kb, lb + lEo[s]);
#pragma unroll
      for (int s = 0; s < 4; ++s) gload_lds16(Bb + gBo[s] + kb, lb + 8192 + lEo[s]);
    }
    __builtin_amdgcn_s_setprio(1);
#pragma unroll
    for (int kk = 0; kk < 2; ++kk)
#pragma unroll
      for (int m = 0; m < 4; ++m)
#pragma unroll
        for (int n = 0; n < 4; ++n)
          acc[m][n] = __builtin_amdgcn_mfma_f32_16x16x32_bf16(af[kk][m], bg[kk][n], acc[m][n], 0, 0, 0);
    __builtin_amdgcn_s_setprio(0);
    if (t + 2 < NT) { SWAIT_VM8(); } else { SWAIT_VM0(); }  // tile t+1 resident
    SCHED_BAR();
    SBAR();                       // B: publish buf((t+1)&1)
  }

  // --- epilogue: C/D layout col = lane&15, row = (lane>>4)*4 + reg
  const int col0 = bn + wc * 64 + l15;
  const int row0 = bm + wr * 64 + (lane >> 4) * 4;
#pragma unroll
  for (int m = 0; m < 4; ++m) {
#pragma unroll
    for (int n = 0; n < 4; ++n) {
      const int cc = col0 + n * 16;
      float bcol = (BIAS_MODE == 2) ? bias[cc] : 0.0f;
#pragma unroll
      for (int r = 0; r < 4; ++r) {
        const int rr = row0 + m * 16 + r;
        float v = acc[m][n][r] + ((BIAS_MODE == 1) ? bias[rr] : bcol);
        if (OUT_F32) ((float*)Cv)[z * sC + (long)rr * N + cc] = v;
        else ((unsigned short*)Cv)[z * sC + (long)rr * N + cc] = f2bf(v);
      }
    }
  }
}

// transpose + f32->bf16: in (z, R, CC) f32 -> out (z, CC, R) bf16. 32x32 tiles.
__global__ __launch_bounds__(256)
void tr_bf_k(const float* __restrict__ in, unsigned short* __restrict__ out, int R, int CC)
{
  __shared__ float t[32][33];
  const long z = blockIdx.z;
  const int r0 = blockIdx.y * 32, c0 = blockIdx.x * 32;
  const float* ip = in + z * (long)R * CC;
  unsigned short* op = out + z * (long)R * CC;
  const int tx = threadIdx.x & 31, ty = threadIdx.x >> 5;
#pragma unroll
  for (int i = 0; i < 32; i += 8)
    t[ty + i][tx] = ip[(long)(r0 + ty + i) * CC + c0 + tx];
  __syncthreads();
  const int oc = threadIdx.x >> 3;
  const int orr = (threadIdx.x & 7) * 4;
  ushort4 o;
  o.x = f2bf(t[orr + 0][oc]); o.y = f2bf(t[orr + 1][oc]);
  o.z = f2bf(t[orr + 2][oc]); o.w = f2bf(t[orr + 3][oc]);
  *(ushort4*)&op[(long)(c0 + oc) * R + r0 + orr] = o;
}

// all 4 weight tensors -> bf16 in one launch. Each weight = 2M f32 = 512K float4.
__global__ void w2bf_k(const float* __restrict__ w0, const float* __restrict__ w1,
                       const float* __restrict__ w2, const float* __restrict__ w3,
                       unsigned short* __restrict__ out)
{
  long g = blockIdx.x * (long)blockDim.x + threadIdx.x;   // grid covers 2M groups
  const long st = (long)gridDim.x * blockDim.x;
  for (; g < 2097152; g += st) {
    const int seg = (int)(g >> 19);
    const long loc = g & 524287;
    const float* src = (seg == 0) ? w0 : (seg == 1) ? w1 : (seg == 2) ? w2 : w3;
    float4 v = *(const float4*)(src + loc * 4);
    ushort4 o; o.x = f2bf(v.x); o.y = f2bf(v.y); o.z = f2bf(v.z); o.w = f2bf(v.w);
    *(ushort4*)(out + g * 4) = o;
  }
}

// one block per row of f (16384 rows x 1024)
__global__ __launch_bounds__(256)
void softmax_k(const float* __restrict__ f, unsigned short* __restrict__ P)
{
  const long row = blockIdx.x;
  const float* fr = f + row * 1024;
  unsigned short* pr = P + row * 1024;
  const int tid = threadIdx.x;
  const int lane = tid & 63, wid = tid >> 6;
  float v[4];
  float mx = -1e30f;
#pragma unroll
  for (int i = 0; i < 4; ++i) { v[i] = fr[tid + i * 256]; mx = fmaxf(mx, v[i]); }
  for (int o = 32; o; o >>= 1) mx = fmaxf(mx, __shfl_xor(mx, o));
  __shared__ float redm[4];
  if (!lane) redm[wid] = mx;
  __syncthreads();
  mx = fmaxf(fmaxf(redm[0], redm[1]), fmaxf(redm[2], redm[3]));
  float s = 0.f;
#pragma unroll
  for (int i = 0; i < 4; ++i) { v[i] = __expf(v[i] - mx); s += v[i]; }
  for (int o = 32; o; o >>= 1) s += __shfl_xor(s, o);
  __shared__ float reds[4];
  if (!lane) reds[wid] = s;
  __syncthreads();
  s = reds[0] + reds[1] + reds[2] + reds[3];
  const float inv = 1.0f / s;
#pragma unroll
  for (int i = 0; i < 4; ++i) pr[tid + i * 256] = f2bf(v[i] * inv);
}

// one block per channel c: mean/var over (B=16, HW=1024) of wy (bf16, (b,C,HW))
__global__ __launch_bounds__(256)
void bn_stats_k(const unsigned short* __restrict__ wy, float* __restrict__ stats)
{
  const int c = blockIdx.x;
  const int tid = threadIdx.x;
  const int lane = tid & 63, wid = tid >> 6;
  float s = 0.f, ss = 0.f;
  for (int b = 0; b < 16; ++b) {
    const unsigned short* p = wy + ((long)b * 2048 + c) * 1024 + tid * 4;
    uint2 u = *(const uint2*)p;
    float v0 = bf2f(u.x & 0xFFFFu), v1 = bf2f(u.x >> 16);
    float v2 = bf2f(u.y & 0xFFFFu), v3 = bf2f(u.y >> 16);
    s += v0 + v1 + v2 + v3;
    ss += v0 * v0 + v1 * v1 + v2 * v2 + v3 * v3;
  }
  for (int o = 32; o; o >>= 1) { s += __shfl_xor(s, o); ss += __shfl_xor(ss, o); }
  __shared__ float rs[4], rss[4];
  if (!lane) { rs[wid] = s; rss[wid] = ss; }
  __syncthreads();
  if (tid == 0) {
    s = rs[0] + rs[1] + rs[2] + rs[3];
    ss = rss[0] + rss[1] + rss[2] + rss[3];
    const float mean = s * (1.0f / 16384.0f);
    const float var = ss * (1.0f / 16384.0f) - mean * mean;
    stats[2 * c] = mean;
    stats[2 * c + 1] = rsqrtf(var + 1e-5f);
  }
}

__global__ void bn_final_k(const unsigned short* __restrict__ wy,
                           const float* __restrict__ x_this,
                           const float* __restrict__ stats,
                           const float* __restrict__ gamma,
                           const float* __restrict__ beta,
                           float* __restrict__ out, long n4)
{
  long i = blockIdx.x * (long)blockDim.x + threadIdx.x;
  const long st = (long)gridDim.x * blockDim.x;
  for (; i < n4; i += st) {
    const long e = i * 4;
    const int c = (int)((e >> 10) & 2047);
    const float mean = stats[2 * c], rstd = stats[2 * c + 1];
    const float ga = gamma[c] * rstd;
    const float be = beta[c] - mean * ga;
    uint2 u = *(const uint2*)(wy + e);
    float4 x = *(const float4*)(x_this + e);
    float4 o;
    o.x = bf2f(u.x & 0xFFFFu) * ga + be + x.x;
    o.y = bf2f(u.x >> 16)     * ga + be + x.y;
    o.z = bf2f(u.y & 0xFFFFu) * ga + be + x.z;
    o.w = bf2f(u.y >> 16)     * ga + be + x.w;
    *(float4*)(out + e) = o;
  }
}

extern "C" void kernel_launch(void* const* d_in, const int* in_sizes, int n_in,
                              void* d_out, int out_size, void* d_ws, size_t ws_size,
                              hipStream_t stream) {
  const float* x_this  = (const float*)d_in[0];
  const float* x_other = (const float*)d_in[1];
  const float* g_w     = (const float*)d_in[2];
  const float* g_b     = (const float*)d_in[3];
  const float* theta_w = (const float*)d_in[4];
  const float* theta_b = (const float*)d_in[5];
  const float* phi_w   = (const float*)d_in[6];
  const float* phi_b   = (const float*)d_in[7];
  const float* wz_w    = (const float*)d_in[8];
  const float* wz_b    = (const float*)d_in[9];
  const float* bn_gamma= (const float*)d_in[10];
  const float* bn_beta = (const float*)d_in[11];
  float* out = (float*)d_out;
  char* ws = (char*)d_ws;
  const size_t MB = 1ull << 20;

  unsigned short* wg  = (unsigned short*)(ws + 0 * MB);   // w2bf fills 0..16 MiB
  unsigned short* wth = (unsigned short*)(ws + 4 * MB);
  unsigned short* wph = (unsigned short*)(ws + 8 * MB);
  unsigned short* wwz = (unsigned short*)(ws + 12 * MB);
  unsigned short* xtT = (unsigned short*)(ws + 16 * MB);   // (16,1024,2048) bf16
  unsigned short* xoT = (unsigned short*)(ws + 80 * MB);   // (16,1024,2048) bf16
  unsigned short* gT  = (unsigned short*)(ws + 144 * MB);  // (16,1024,1024)
  unsigned short* thT = (unsigned short*)(ws + 176 * MB);
  unsigned short* phT = (unsigned short*)(ws + 208 * MB);
  float*          fb  = (float*)         (ws + 16 * MB);   // reuse xtT (64 MiB f32)
  unsigned short* P   = (unsigned short*)(ws + 80 * MB);   // reuse xoT (32 MiB)
  unsigned short* yT  = (unsigned short*)(ws + 112 * MB);  // reuse xoT (32 MiB)
  unsigned short* wy  = (unsigned short*)(ws + 176 * MB);  // reuse thT+phT (64 MiB)
  float*          st  = (float*)         (ws + 240 * MB);

  const long S1M = 1l << 20;   // 1024*1024
  const long S2M = 2l << 20;   // 2048*1024

  // weights -> bf16 (one launch)
  w2bf_k<<<dim3(2048), dim3(256), 0, stream>>>(g_w, theta_w, phi_w, wz_w, wg);
  // x transposes -> bf16 (HW x C per batch)
  tr_bf_k<<<dim3(32, 64, 16), dim3(256), 0, stream>>>(x_this,  xtT, 2048, 1024);
  tr_bf_k<<<dim3(32, 64, 16), dim3(256), 0, stream>>>(x_other, xoT, 2048, 1024);

  // conv^T GEMMs: (HW x C) @ (IC x C)^T -> (HW x IC), col-bias. grid 8x8x16=1024
  mm_bt<0, 2><<<dim3(1024), dim3(256), 0, stream>>>(xtT, wg,  gT,  g_b,     1024, 2048, S2M, 0, S1M, 8, 8);
  mm_bt<0, 2><<<dim3(1024), dim3(256), 0, stream>>>(xtT, wth, thT, theta_b, 1024, 2048, S2M, 0, S1M, 8, 8);
  mm_bt<0, 2><<<dim3(1024), dim3(256), 0, stream>>>(xoT, wph, phT, phi_b,   1024, 2048, S2M, 0, S1M, 8, 8);
  // f = phT @ thT^T (f32 out)
  mm_bt<1, 0><<<dim3(1024), dim3(256), 0, stream>>>(phT, thT, fb, nullptr, 1024, 1024, S1M, S1M, S1M, 8, 8);
  // P = softmax(f)
  softmax_k<<<dim3(16384), dim3(256), 0, stream>>>(fb, P);
  // yT = gT @ P^T
  mm_bt<0, 0><<<dim3(1024), dim3(256), 0, stream>>>(gT, P, yT, nullptr, 1024, 1024, S1M, S1M, S1M, 8, 8);
  // wy = wz @ yT^T + wz_b (row-bias). grid 8x16x16=2048
  mm_bt<0, 1><<<dim3(2048), dim3(256), 0, stream>>>(wwz, yT, wy, wz_b, 1024, 1024, 0, S1M, S2M, 8, 16);
  // BN + residual
  bn_stats_k<<<dim3(2048), dim3(256), 0, stream>>>(wy, st);
  bn_final_k<<<dim3(4096), dim3(256), 0, stream>>>(wy, x_this, st, bn_gamma, bn_beta, out, 33554432 / 4);
  (void)ws_size; (void)n_in; (void)in_sizes; (void)out_size;
  (void)wth; (void)wph;
}

// Round 10
// 808.454 us; speedup vs baseline: 12.5114x; 1.0026x over previous
//
#include <hip/hip_runtime.h>

// Non-local block: B=16, C=2048, IC=HW=1024.
// R9: GEMM moved to 256x256 tile, 8 waves (512 thr), BK=64, 128 KiB LDS dbuf,
// 4-sub-phase interleaved compute (T3-style) on the R5-verified counted-vmcnt
// barrier skeleton {SBAR -> stage(t+2) -> vmcnt(8) -> SBAR}. T1 XCD swizzle,
// T5 setprio per MFMA cluster. Same math pipeline:
//   xtT/xoT = transpose(x) bf16 -> gT/thT/phT = xT @ w^T + b -> f = phT@thT^T
//   -> softmax -> yT = gT@P^T -> wy = wz@yT^T + b -> BN -> +x_this.

typedef __attribute__((ext_vector_type(4))) float f32x4;
typedef __attribute__((ext_vector_type(8))) short bf16x8;

__device__ __forceinline__ float bf2f(unsigned s16) {
  union { unsigned u; float f; } v; v.u = s16 << 16; return v.f;
}
__device__ __forceinline__ unsigned short f2bf(float f) {
  union { float f; unsigned u; } v; v.f = f;
  unsigned r = v.u + 0x7FFFu + ((v.u >> 16) & 1u);
  return (unsigned short)(r >> 16);
}

__device__ __forceinline__ void gload_lds16(const unsigned short* g, unsigned short* l) {
  __builtin_amdgcn_global_load_lds((const __attribute__((address_space(1))) void*)g,
                                   (__attribute__((address_space(3))) void*)l, 16, 0, 0);
}

#define SWAIT_VM8()   asm volatile("s_waitcnt vmcnt(8)" ::: "memory")
#define SWAIT_VM0()   asm volatile("s_waitcnt vmcnt(0)" ::: "memory")
#define SWAIT_LGKM0() asm volatile("s_waitcnt lgkmcnt(0)" ::: "memory")
#define SCHED_BAR()   __builtin_amdgcn_sched_barrier(0)
#define SBAR()        __builtin_amdgcn_s_barrier()
#define MFMA16(a, b, c) __builtin_amdgcn_mfma_f32_16x16x32_bf16(a, b, c, 0, 0, 0)

// C(MxN) = A(MxK) @ Bt(NxK)^T, bf16 in, fp32 accum.
// 256x256 tile, 8 waves (2M x 4N, 128x64 per wave), BK=64, dbuf LDS 128 KiB.
// LDS slot-swizzle: 16B slot s of row r holds global k-slot s ^ (r&7)
// (pre-swizzled GLOBAL source, linear LDS dest — rule #21). ks=1 offsets = ks=0 ^ 32.
// Per K-tile: 4 phases {ds_read, lgkm0, 16 MFMA}; boundary {SBAR, stage t+2,
// vmcnt(8), SBAR} — tile t+1 in flight across the whole compute (never vmcnt 0 in loop).
template<int OUT_F32, int BIAS_MODE>   // BIAS_MODE: 0 none, 1 bias[row], 2 bias[col]
__global__ __launch_bounds__(512, 2)
void mm_bt(const unsigned short* __restrict__ A, const unsigned short* __restrict__ Bt,
           void* __restrict__ Cv, const float* __restrict__ bias,
           int N, int K, long sA, long sB, long sC, int nbx, int nby)
{
  __shared__ __align__(16) unsigned short lds[65536];  // buf b: A@[b*32768), B@[b*32768+16384)
  const int tid = threadIdx.x;
  const int wave = tid >> 6, lane = tid & 63;

  // --- XCD swizzle (nwg % 8 == 0 for all launches)
  const int nwg = nbx * nby * 16;
  const int cpx = nwg >> 3;
  const int swz = (blockIdx.x & 7) * cpx + (blockIdx.x >> 3);
  const int bx = swz % nbx;
  const int rem = swz / nbx;
  const int by = rem % nby;
  const long z = rem / nby;
  const int bm = by * 256, bn = bx * 256;

  const unsigned short* Ab = A + z * sA;
  const unsigned short* Bb = Bt + z * sB;

  // --- staging: 4 A-loads + 4 B-loads per thread per K-tile (half = 32 KiB each).
  // 16B-slot q = j*512 + tid -> row = q>>3, slot = q&7; LDS elem = q*8;
  // global k-slot = slot ^ (row&7).
  int gAo[4], gBo[4], lEo[4];
#pragma unroll
  for (int j = 0; j < 4; ++j) {
    const int q = j * 512 + tid;
    const int row = q >> 3, sl = q & 7;
    const int gsl = sl ^ (row & 7);
    gAo[j] = (bm + row) * K + gsl * 8;
    gBo[j] = (bn + row) * K + gsl * 8;
    lEo[j] = q * 8;
  }

  // --- fragment read offsets (ks=0; ks=1 = ^32 since slot bit2 flips)
  const int wr = wave >> 2, wc = wave & 3;
  const int l15 = lane & 15, kgl = lane >> 4;
  int aoff[8], boff[4];
#pragma unroll
  for (int m = 0; m < 8; ++m) {
    const int ra = wr * 128 + m * 16 + l15;
    aoff[m] = ra * 64 + (kgl ^ (ra & 7)) * 8;
  }
#pragma unroll
  for (int n = 0; n < 4; ++n) {
    const int rb = wc * 64 + n * 16 + l15;
    boff[n] = 16384 + rb * 64 + (kgl ^ (rb & 7)) * 8;
  }

  const int NT = K >> 6;

  // --- prologue: stage tile0 -> buf0, tile1 -> buf1; vmcnt(8) = tile0 resident
  {
#pragma unroll
    for (int j = 0; j < 4; ++j) gload_lds16(Ab + gAo[j], &lds[lEo[j]]);
#pragma unroll
    for (int j = 0; j < 4; ++j) gload_lds16(Bb + gBo[j], &lds[16384 + lEo[j]]);
#pragma unroll
    for (int j = 0; j < 4; ++j) gload_lds16(Ab + gAo[j] + 64, &lds[32768 + lEo[j]]);
#pragma unroll
    for (int j = 0; j < 4; ++j) gload_lds16(Bb + gBo[j] + 64, &lds[32768 + 16384 + lEo[j]]);
  }
  SWAIT_VM8(); SCHED_BAR();
  SBAR();

  f32x4 acc[8][4];
#pragma unroll
  for (int i = 0; i < 8; ++i)
#pragma unroll
    for (int j = 0; j < 4; ++j) acc[i][j] = (f32x4)0.f;

  for (int t = 0; t < NT; ++t) {
    const int bufo = (t & 1) * 32768;
    bf16x8 af[8], b0, b1;
    // P1: ks=0, n=0..1
#pragma unroll
    for (int m = 0; m < 8; ++m) af[m] = *(const bf16x8*)&lds[bufo + aoff[m]];
    b0 = *(const bf16x8*)&lds[bufo + boff[0]];
    b1 = *(const bf16x8*)&lds[bufo + boff[1]];
    SWAIT_LGKM0(); SCHED_BAR();
    __builtin_amdgcn_s_setprio(1);
#pragma unroll
    for (int m = 0; m < 8; ++m) {
      acc[m][0] = MFMA16(af[m], b0, acc[m][0]);
      acc[m][1] = MFMA16(af[m], b1, acc[m][1]);
    }
    __builtin_amdgcn_s_setprio(0);
    // P2: ks=0, n=2..3
    b0 = *(const bf16x8*)&lds[bufo + boff[2]];
    b1 = *(const bf16x8*)&lds[bufo + boff[3]];
    SWAIT_LGKM0(); SCHED_BAR();
    __builtin_amdgcn_s_setprio(1);
#pragma unroll
    for (int m = 0; m < 8; ++m) {
      acc[m][2] = MFMA16(af[m], b0, acc[m][2]);
      acc[m][3] = MFMA16(af[m], b1, acc[m][3]);
    }
    __builtin_amdgcn_s_setprio(0);
    // P3: ks=1, n=0..1
#pragma unroll
    for (int m = 0; m < 8; ++m) af[m] = *(const bf16x8*)&lds[bufo + (aoff[m] ^ 32)];
    b0 = *(const bf16x8*)&lds[bufo + (boff[0] ^ 32)];
    b1 = *(const bf16x8*)&lds[bufo + (boff[1] ^ 32)];
    SWAIT_LGKM0(); SCHED_BAR();
    __builtin_amdgcn_s_setprio(1);
#pragma unroll
    for (int m = 0; m < 8; ++m) {
      acc[m][0] = MFMA16(af[m], b0, acc[m][0]);
      acc[m][1] = MFMA16(af[m], b1, acc[m][1]);
    }
    __builtin_amdgcn_s_setprio(0);
    // P4: ks=1, n=2..3
    b0 = *(const bf16x8*)&lds[bufo + (boff[2] ^ 32)];
    b1 = *(const bf16x8*)&lds[bufo + (boff[3] ^ 32)];
    SWAIT_LGKM0(); SCHED_BAR();
    __builtin_amdgcn_s_setprio(1);
#pragma unroll
    for (int m = 0; m < 8; ++m) {
      acc[m][2] = MFMA16(af[m], b0, acc[m][2]);
      acc[m][3] = MFMA16(af[m], b1, acc[m][3]);
    }
    __builtin_amdgcn_s_setprio(0);
    // --- boundary: all waves done reading buf[t&1]; refill it with tile t+2
    SBAR();
    if (t + 2 < NT) {
      const long kb = (long)(t + 2) * 64;
#pragma unroll
      for (int j = 0; j < 4; ++j) gload_lds16(Ab + gAo[j] + kb, &lds[bufo + lEo[j]]);
#pragma unroll
      for (int j = 0; j < 4; ++j) gload_lds16(Bb + gBo[j] + kb, &lds[bufo + 16384 + lEo[j]]);
      SWAIT_VM8();                 // retire tile t+1's 8 loads; t+2's stay in flight
    } else {
      SWAIT_VM0();                 // drain at the tail
    }
    SCHED_BAR();
    SBAR();                        // publish buf[(t+1)&1]
  }

  // --- epilogue: C/D layout col = lane&15, row = (lane>>4)*4 + reg
  const int col0 = bn + wc * 64 + l15;
  const int row0 = bm + wr * 128 + (lane >> 4) * 4;
#pragma unroll
  for (int m = 0; m < 8; ++m) {
#pragma unroll
    for (int n = 0; n < 4; ++n) {
      const int cc = col0 + n * 16;
      float bcol = (BIAS_MODE == 2) ? bias[cc] : 0.0f;
#pragma unroll
      for (int r = 0; r < 4; ++r) {
        const int rr = row0 + m * 16 + r;
        float v = acc[m][n][r] + ((BIAS_MODE == 1) ? bias[rr] : bcol);
        if (OUT_F32) ((float*)Cv)[z * sC + (long)rr * N + cc] = v;
        else ((unsigned short*)Cv)[z * sC + (long)rr * N + cc] = f2bf(v);
      }
    }
  }
}

// transpose + f32->bf16: in (z, R, CC) f32 -> out (z, CC, R) bf16. 32x32 tiles.
__global__ __launch_bounds__(256)
void tr_bf_k(const float* __restrict__ in, unsigned short* __restrict__ out, int R, int CC)
{
  __shared__ float t[32][33];
  const long z = blockIdx.z;
  const int r0 = blockIdx.y * 32, c0 = blockIdx.x * 32;
  const float* ip = in + z * (long)R * CC;
  unsigned short* op = out + z * (long)R * CC;
  const int tx = threadIdx.x & 31, ty = threadIdx.x >> 5;
#pragma unroll
  for (int i = 0; i < 32; i += 8)
    t[ty + i][tx] = ip[(long)(r0 + ty + i) * CC + c0 + tx];
  __syncthreads();
  const int oc = threadIdx.x >> 3;
  const int orr = (threadIdx.x & 7) * 4;
  ushort4 o;
  o.x = f2bf(t[orr + 0][oc]); o.y = f2bf(t[orr + 1][oc]);
  o.z = f2bf(t[orr + 2][oc]); o.w = f2bf(t[orr + 3][oc]);
  *(ushort4*)&op[(long)(c0 + oc) * R + r0 + orr] = o;
}

// all 4 weight tensors -> bf16 in one launch.
__global__ void w2bf_k(const float* __restrict__ w0, const float* __restrict__ w1,
                       const float* __restrict__ w2, const float* __restrict__ w3,
                       unsigned short* __restrict__ out)
{
  long g = blockIdx.x * (long)blockDim.x + threadIdx.x;
  const long st = (long)gridDim.x * blockDim.x;
  for (; g < 2097152; g += st) {
    const int seg = (int)(g >> 19);
    const long loc = g & 524287;
    const float* src = (seg == 0) ? w0 : (seg == 1) ? w1 : (seg == 2) ? w2 : w3;
    float4 v = *(const float4*)(src + loc * 4);
    ushort4 o; o.x = f2bf(v.x); o.y = f2bf(v.y); o.z = f2bf(v.z); o.w = f2bf(v.w);
    *(ushort4*)(out + g * 4) = o;
  }
}

// one block per row of f (16384 rows x 1024)
__global__ __launch_bounds__(256)
void softmax_k(const float* __restrict__ f, unsigned short* __restrict__ P)
{
  const long row = blockIdx.x;
  const float* fr = f + row * 1024;
  unsigned short* pr = P + row * 1024;
  const int tid = threadIdx.x;
  const int lane = tid & 63, wid = tid >> 6;
  float v[4];
  float mx = -1e30f;
#pragma unroll
  for (int i = 0; i < 4; ++i) { v[i] = fr[tid + i * 256]; mx = fmaxf(mx, v[i]); }
  for (int o = 32; o; o >>= 1) mx = fmaxf(mx, __shfl_xor(mx, o));
  __shared__ float redm[4];
  if (!lane) redm[wid] = mx;
  __syncthreads();
  mx = fmaxf(fmaxf(redm[0], redm[1]), fmaxf(redm[2], redm[3]));
  float s = 0.f;
#pragma unroll
  for (int i = 0; i < 4; ++i) { v[i] = __expf(v[i] - mx); s += v[i]; }
  for (int o = 32; o; o >>= 1) s += __shfl_xor(s, o);
  __shared__ float reds[4];
  if (!lane) reds[wid] = s;
  __syncthreads();
  s = reds[0] + reds[1] + reds[2] + reds[3];
  const float inv = 1.0f / s;
#pragma unroll
  for (int i = 0; i < 4; ++i) pr[tid + i * 256] = f2bf(v[i] * inv);
}

// one block per channel c: mean/var over (B=16, HW=1024) of wy (bf16, (b,C,HW))
__global__ __launch_bounds__(256)
void bn_stats_k(const unsigned short* __restrict__ wy, float* __restrict__ stats)
{
  const int c = blockIdx.x;
  const int tid = threadIdx.x;
  const int lane = tid & 63, wid = tid >> 6;
  float s = 0.f, ss = 0.f;
  for (int b = 0; b < 16; ++b) {
    const unsigned short* p = wy + ((long)b * 2048 + c) * 1024 + tid * 4;
    uint2 u = *(const uint2*)p;
    float v0 = bf2f(u.x & 0xFFFFu), v1 = bf2f(u.x >> 16);
    float v2 = bf2f(u.y & 0xFFFFu), v3 = bf2f(u.y >> 16);
    s += v0 + v1 + v2 + v3;
    ss += v0 * v0 + v1 * v1 + v2 * v2 + v3 * v3;
  }
  for (int o = 32; o; o >>= 1) { s += __shfl_xor(s, o); ss += __shfl_xor(ss, o); }
  __shared__ float rs[4], rss[4];
  if (!lane) { rs[wid] = s; rss[wid] = ss; }
  __syncthreads();
  if (tid == 0) {
    s = rs[0] + rs[1] + rs[2] + rs[3];
    ss = rss[0] + rss[1] + rss[2] + rss[3];
    const float mean = s * (1.0f / 16384.0f);
    const float var = ss * (1.0f / 16384.0f) - mean * mean;
    stats[2 * c] = mean;
    stats[2 * c + 1] = rsqrtf(var + 1e-5f);
  }
}

__global__ void bn_final_k(const unsigned short* __restrict__ wy,
                           const float* __restrict__ x_this,
                           const float* __restrict__ stats,
                           const float* __restrict__ gamma,
                           const float* __restrict__ beta,
                           float* __restrict__ out, long n4)
{
  long i = blockIdx.x * (long)blockDim.x + threadIdx.x;
  const long st = (long)gridDim.x * blockDim.x;
  for (; i < n4; i += st) {
    const long e = i * 4;
    const int c = (int)((e >> 10) & 2047);
    const float mean = stats[2 * c], rstd = stats[2 * c + 1];
    const float ga = gamma[c] * rstd;
    const float be = beta[c] - mean * ga;
    uint2 u = *(const uint2*)(wy + e);
    float4 x = *(const float4*)(x_this + e);
    float4 o;
    o.x = bf2f(u.x & 0xFFFFu) * ga + be + x.x;
    o.y = bf2f(u.x >> 16)     * ga + be + x.y;
    o.z = bf2f(u.y & 0xFFFFu) * ga + be + x.z;
    o.w = bf2f(u.y >> 16)     * ga + be + x.w;
    *(float4*)(out + e) = o;
  }
}

extern "C" void kernel_launch(void* const* d_in, const int* in_sizes, int n_in,
                              void* d_out, int out_size, void* d_ws, size_t ws_size,
                              hipStream_t stream) {
  const float* x_this  = (const float*)d_in[0];
  const float* x_other = (const float*)d_in[1];
  const float* g_w     = (const float*)d_in[2];
  const float* g_b     = (const float*)d_in[3];
  const float* theta_w = (const float*)d_in[4];
  const float* theta_b = (const float*)d_in[5];
  const float* phi_w   = (const float*)d_in[6];
  const float* phi_b   = (const float*)d_in[7];
  const float* wz_w    = (const float*)d_in[8];
  const float* wz_b    = (const float*)d_in[9];
  const float* bn_gamma= (const float*)d_in[10];
  const float* bn_beta = (const float*)d_in[11];
  float* out = (float*)d_out;
  char* ws = (char*)d_ws;
  const size_t MB = 1ull << 20;

  unsigned short* wg  = (unsigned short*)(ws + 0 * MB);   // w2bf fills 0..16 MiB
  unsigned short* wth = (unsigned short*)(ws + 4 * MB);
  unsigned short* wph = (unsigned short*)(ws + 8 * MB);
  unsigned short* wwz = (unsigned short*)(ws + 12 * MB);
  unsigned short* xtT = (unsigned short*)(ws + 16 * MB);   // (16,1024,2048) bf16
  unsigned short* xoT = (unsigned short*)(ws + 80 * MB);   // (16,1024,2048) bf16
  unsigned short* gT  = (unsigned short*)(ws + 144 * MB);  // (16,1024,1024)
  unsigned short* thT = (unsigned short*)(ws + 176 * MB);
  unsigned short* phT = (unsigned short*)(ws + 208 * MB);
  float*          fb  = (float*)         (ws + 16 * MB);   // reuse xtT (64 MiB f32)
  unsigned short* P   = (unsigned short*)(ws + 80 * MB);   // reuse xoT (32 MiB)
  unsigned short* yT  = (unsigned short*)(ws + 112 * MB);  // reuse xoT (32 MiB)
  unsigned short* wy  = (unsigned short*)(ws + 176 * MB);  // reuse thT+phT (64 MiB)
  float*          st  = (float*)         (ws + 240 * MB);

  const long S1M = 1l << 20;   // 1024*1024
  const long S2M = 2l << 20;   // 2048*1024

  // weights -> bf16 (one launch)
  w2bf_k<<<dim3(2048), dim3(256), 0, stream>>>(g_w, theta_w, phi_w, wz_w, wg);
  // x transposes -> bf16 (HW x C per batch)
  tr_bf_k<<<dim3(32, 64, 16), dim3(256), 0, stream>>>(x_this,  xtT, 2048, 1024);
  tr_bf_k<<<dim3(32, 64, 16), dim3(256), 0, stream>>>(x_other, xoT, 2048, 1024);

  // conv^T GEMMs: (HW x C) @ (IC x C)^T -> (HW x IC), col-bias. grid 4x4x16=256
  mm_bt<0, 2><<<dim3(256), dim3(512), 0, stream>>>(xtT, wg,  gT,  g_b,     1024, 2048, S2M, 0, S1M, 4, 4);
  mm_bt<0, 2><<<dim3(256), dim3(512), 0, stream>>>(xtT, wth, thT, theta_b, 1024, 2048, S2M, 0, S1M, 4, 4);
  mm_bt<0, 2><<<dim3(256), dim3(512), 0, stream>>>(xoT, wph, phT, phi_b,   1024, 2048, S2M, 0, S1M, 4, 4);
  // f = phT @ thT^T (f32 out)
  mm_bt<1, 0><<<dim3(256), dim3(512), 0, stream>>>(phT, thT, fb, nullptr, 1024, 1024, S1M, S1M, S1M, 4, 4);
  // P = softmax(f)
  softmax_k<<<dim3(16384), dim3(256), 0, stream>>>(fb, P);
  // yT = gT @ P^T
  mm_bt<0, 0><<<dim3(256), dim3(512), 0, stream>>>(gT, P, yT, nullptr, 1024, 1024, S1M, S1M, S1M, 4, 4);
  // wy = wz @ yT^T + wz_b (row-bias). grid 4x8x16=512
  mm_bt<0, 1><<<dim3(512), dim3(512), 0, stream>>>(wwz, yT, wy, wz_b, 1024, 1024, 0, S1M, S2M, 4, 8);
  // BN + residual
  bn_stats_k<<<dim3(2048), dim3(256), 0, stream>>>(wy, st);
  bn_final_k<<<dim3(4096), dim3(256), 0, stream>>>(wy, x_this, st, bn_gamma, bn_beta, out, 33554432 / 4);
  (void)ws_size; (void)n_in; (void)in_sizes; (void)out_size;
  (void)wth; (void)wph;
}